// Round 2
// baseline (389.618 us; speedup 1.0000x reference)
//
#include <hip/hip_runtime.h>
#include <hip/hip_fp16.h>

// layer_3d_dep_53300544143949 — MI355X (gfx950)
// B=64, C=8, O=8, M=32, K=32, NR=8, NT=8. All inputs and output FLOAT32.
// R5b structure (R5 + nontemporal-store type fix):
//   k1a: vectorized m-mean reduce, block=(b,c), 32B/lane loads -> mc[b,c,2048] (ws, 4MB)
//        + stats zero (block 0)
//   k1b: in-place P2 transform mc -> a2pre (thread owns its 8 addresses; race-free)
//   k2:  main fold + attention (unchanged math, __launch_bounds__(256,2), VGPR 128)
//        MODE 0: f32 pre-BN -> d_out (fallback, ws < 12.6MB)
//        MODE 1: fp16 pre-BN -> ws staging (ws >= 71.3MB)
//        MODE 2: fp16 pre-BN split: planes b*8+o < 64 -> ws (8MB), rest -> d_out at byte 2e
//   k3:  BN normalize. MODE 1: single launch from ws. MODE 2: 4-launch cascade over
//        element ranges [N/2,N),[N/4,N/2),[N/8,N/4),[0,N/8) — each launch's f32 writes
//        (bytes [4e)) are disjoint from its own fp16 reads (bytes [2e)); launch order
//        retires every region before it is overwritten. Non-temporal final stores.
// ws: [0,256) stats | [256, 256+4MB) mc/a2pre f32 | [+4MB, ...) fp16 staging

using u16 = unsigned short;
using u32 = unsigned int;
typedef float f32x4 __attribute__((ext_vector_type(4)));

#define NTOT 33554432  // total output elements = 64*8*32*32*8*8

__device__ __forceinline__ void ld8f(const float* p, float* f) {
  float4 a = *(const float4*)p;
  float4 b = *(const float4*)(p + 4);
  f[0] = a.x; f[1] = a.y; f[2] = a.z; f[3] = a.w;
  f[4] = b.x; f[5] = b.y; f[6] = b.z; f[7] = b.w;
}
__device__ __forceinline__ void st8f(float* p, const float* f) {
  *(float4*)p = make_float4(f[0], f[1], f[2], f[3]);
  *(float4*)(p + 4) = make_float4(f[4], f[5], f[6], f[7]);
}
__device__ __forceinline__ void st8f_nt(float* p, const float* f) {
  f32x4 a = {f[0], f[1], f[2], f[3]};
  f32x4 b = {f[4], f[5], f[6], f[7]};
  __builtin_nontemporal_store(a, (f32x4*)p);
  __builtin_nontemporal_store(b, (f32x4*)(p + 4));
}
__device__ __forceinline__ u16 f2h(float f) {
  __half h = __float2half_rn(f);
  return *(u16*)&h;
}
__device__ __forceinline__ float h2f(u16 x) {
  __half h = *(__half*)&x;
  return __half2float(h);
}
__device__ __forceinline__ float fast_tanh(float x) {
  float e = __expf(2.0f * x);
  return 1.0f - 2.0f / (e + 1.0f);
}

// ---------------- k1a: m-mean reduce (vectorized) ----------------
// grid 512 = b*8+c; 256 thr; thread owns j = tid*8..tid*8+7.
// Reads A[b,c,:, j..j+7] (32 x 32B contiguous-per-wave loads), writes mc[b,c,j..j+7].
__global__ void k1a_mmean(const float* __restrict__ A, float* __restrict__ mcab,
                          float* __restrict__ stats) {
  const int b = blockIdx.x >> 3;
  const int c = blockIdx.x & 7;
  const int tid = threadIdx.x;
  if (blockIdx.x == 0 && tid < 16) stats[tid] = 0.0f;
  const float* base = A + (size_t)(b * 8 + c) * 65536 + tid * 8;
  float acc[8];
#pragma unroll
  for (int t = 0; t < 8; ++t) acc[t] = 0.0f;
#pragma unroll
  for (int m = 0; m < 32; ++m) {
    float ar[8];
    ld8f(base + m * 2048, ar);
#pragma unroll
    for (int t = 0; t < 8; ++t) acc[t] += ar[t];
  }
#pragma unroll
  for (int t = 0; t < 8; ++t) acc[t] *= (1.0f / 32.0f);
  st8f(mcab + (size_t)(b * 8 + c) * 2048 + tid * 8, acc);
}

// ---------------- k1b: in-place P2 transform mc -> a2pre ----------------
// grid 512 = b*8+jq; 256 thr; thread owns (b, j): reads mc[b,0..8,j], writes
// a2pre[b,0..8,j] over the same 8 addresses. Address set is thread-private ->
// no cross-thread hazard; every store depends on all 8 loads -> no reorder.
__global__ void k1b_p2(float* __restrict__ mcab, const float* __restrict__ P2) {
  const int b = blockIdx.x >> 3;
  const int j = (blockIdx.x & 7) * 256 + threadIdx.x;
  float mc[8];
#pragma unroll
  for (int c = 0; c < 8; ++c) mc[c] = mcab[(size_t)(b * 8 + c) * 2048 + j];
  float a2[8];
#pragma unroll
  for (int o = 0; o < 8; ++o) {
    float s = 0.0f;
#pragma unroll
    for (int c = 0; c < 8; ++c) s = fmaf(P2[o * 8 + c], mc[c], s);
    a2[o] = 0.1f * s;
  }
#pragma unroll
  for (int o = 0; o < 8; ++o) mcab[(size_t)(b * 8 + o) * 2048 + j] = a2[o];
}

// ---------------- k2: main ----------------
// grid 2048 = (b<<5)|m; 256 thr. (k,r): k=tid>>3, r=tid&7.
template <int MODE>
__global__ __launch_bounds__(256, 2) void k2_main(
    const float* __restrict__ A,
    const float* __restrict__ a2pre,
    const float* __restrict__ P1,
    const float* __restrict__ P3,
    const float* __restrict__ P4,
    const float* __restrict__ P5,
    const float* __restrict__ Wq,
    const float* __restrict__ Wk,
    float* __restrict__ outp,      // MODE 0: f32 out; MODE 2: also fp16 target
    u16* __restrict__ xb,          // MODE 1: full staging; MODE 2: planes < 64
    float* __restrict__ stats) {
  __shared__ float qb[8 * 260];
  __shared__ float kb[8 * 260];
  __shared__ float vb[8 * 260];
  __shared__ float a5b[8 * 260];
  __shared__ float sred[64];

  const int tid = threadIdx.x;
  const int b = blockIdx.x >> 5;
  const int m = blockIdx.x & 31;
  const int k = tid >> 3;
  const int r = tid & 7;

  float acc[8][8];
  float acc3[8];
  float qv[8], kv[8], vv[8];
#pragma unroll
  for (int o = 0; o < 8; ++o) {
    acc3[o] = 0.0f;
#pragma unroll
    for (int t = 0; t < 8; ++t) acc[o][t] = 0.0f;
  }
#pragma unroll
  for (int t = 0; t < 8; ++t) { qv[t] = 0.0f; kv[t] = 0.0f; vv[t] = 0.0f; }

  // Single c-loop: load A row; trc via lane-xor means; fold A1/A4 per-t,
  // A3 hoisted to scalar acc3[o]; accumulate qkv (o = r lane mapping).
#pragma unroll
  for (int c = 0; c < 8; ++c) {
    float ar[8];
    ld8f(A + ((size_t)((b * 8 + c) * 32 + m) * 2048 + tid * 8), ar);
    float trc[8];
#pragma unroll
    for (int t = 0; t < 8; ++t) {
      float x = ar[t];
      x += __shfl_xor(x, 1, 64);
      x += __shfl_xor(x, 2, 64);
      x += __shfl_xor(x, 4, 64);
      trc[t] = x * 0.125f;
    }
    const float mtc = (ar[0] + ar[1] + ar[2] + ar[3] +
                       ar[4] + ar[5] + ar[6] + ar[7]) * 0.125f;
#pragma unroll
    for (int o = 0; o < 8; ++o) {
      const float w1 = P1[o * 8 + c];
      const float w4 = 0.5f * P4[o * 8 + c];
      acc3[o] = fmaf(0.1f * P3[o * 8 + c], mtc, acc3[o]);
#pragma unroll
      for (int t = 0; t < 8; ++t)
        acc[o][t] = fmaf(w1, ar[t], fmaf(w4, trc[t], acc[o][t]));
    }
    const float wq = Wq[r * 8 + c];
    const float wk = Wk[r * 8 + c];
    const float wv = P5[r * 8 + c];
#pragma unroll
    for (int t = 0; t < 8; ++t) {
      qv[t] = fmaf(wq, trc[t], qv[t]);
      kv[t] = fmaf(wk, trc[t], kv[t]);
      vv[t] = fmaf(wv, trc[t], vv[t]);
    }
  }

  // A2 (precomputed, m-independent) + A3 broadcast
#pragma unroll
  for (int o = 0; o < 8; ++o) {
    float a2v[8];
    ld8f(a2pre + ((size_t)(b * 8 + o) * 2048 + tid * 8), a2v);
#pragma unroll
    for (int t = 0; t < 8; ++t) acc[o][t] += a2v[t] + acc3[o];
  }

  st8f(&qb[r * 260 + k * 8], qv);
  st8f(&kb[r * 260 + k * 8], kv);
  st8f(&vb[r * 260 + k * 8], vv);
  __syncthreads();

  // Attention: thread = (o, kq, lo): 4 k-rows x 8 l-rows register tile
  {
    const int o = tid >> 5;
    const int kq = (tid >> 2) & 7;
    const int lo = tid & 3;
    float qf[4][8];
#pragma unroll
    for (int kl = 0; kl < 4; ++kl)
      ld8f(&qb[o * 260 + (kq * 4 + kl) * 8], qf[kl]);
    float a5p[4][8];
#pragma unroll
    for (int kl = 0; kl < 4; ++kl)
#pragma unroll
      for (int t = 0; t < 8; ++t) a5p[kl][t] = 0.0f;

#pragma unroll
    for (int ll = 0; ll < 8; ++ll) {
      const int l = lo * 8 + ll;
      float krw[8];
      ld8f(&kb[o * 260 + l * 8], krw);
      float al[4];
#pragma unroll
      for (int kl = 0; kl < 4; ++kl) {
        float s = 0.0f;
#pragma unroll
        for (int t = 0; t < 8; ++t) s = fmaf(qf[kl][t], krw[t], s);
        al[kl] = fast_tanh(s * 0.125f);  // /NT
      }
      float vrw[8];
      ld8f(&vb[o * 260 + l * 8], vrw);
#pragma unroll
      for (int kl = 0; kl < 4; ++kl)
#pragma unroll
        for (int t = 0; t < 8; ++t)
          a5p[kl][t] = fmaf(al[kl], vrw[t], a5p[kl][t]);
    }
#pragma unroll
    for (int kl = 0; kl < 4; ++kl)
#pragma unroll
      for (int t = 0; t < 8; ++t) {
        float x = a5p[kl][t];
        x += __shfl_xor(x, 1, 64);
        x += __shfl_xor(x, 2, 64);
        a5p[kl][t] = x * 0.0625f;  // 2/Kd
      }
#pragma unroll
    for (int kl = 0; kl < 4; ++kl) {
      const float w0 = lo == 0 ? a5p[kl][0] : lo == 1 ? a5p[kl][2]
                      : lo == 2 ? a5p[kl][4] : a5p[kl][6];
      const float w1 = lo == 0 ? a5p[kl][1] : lo == 1 ? a5p[kl][3]
                      : lo == 2 ? a5p[kl][5] : a5p[kl][7];
      *(float2*)&a5b[o * 260 + (kq * 4 + kl) * 8 + lo * 2] = make_float2(w0, w1);
    }
  }
  __syncthreads();

  // Epilogue: +A5, ReLU, stats, store pre-BN
  float psum[8], psq[8];
#pragma unroll
  for (int o = 0; o < 8; ++o) { psum[o] = 0.0f; psq[o] = 0.0f; }
  const size_t outbase = (size_t)(b * 256 + m) * 2048 + tid * 8;
#pragma unroll
  for (int o = 0; o < 8; ++o) {
    float a5f[8];
    ld8f(&a5b[o * 260 + k * 8], a5f);
    float x8[8];
#pragma unroll
    for (int t = 0; t < 8; ++t) {
      float x = acc[o][t] + a5f[t];
      x = fmaxf(x, 0.0f);
      psum[o] += x;
      psq[o] = fmaf(x, x, psq[o]);
      x8[t] = x;
    }
    const size_t idx = outbase + (size_t)o * 65536;
    if (MODE == 0) {
      st8f(outp + idx, x8);
    } else {
      uint4 u;
      u.x = (u32)f2h(x8[0]) | ((u32)f2h(x8[1]) << 16);
      u.y = (u32)f2h(x8[2]) | ((u32)f2h(x8[3]) << 16);
      u.z = (u32)f2h(x8[4]) | ((u32)f2h(x8[5]) << 16);
      u.w = (u32)f2h(x8[6]) | ((u32)f2h(x8[7]) << 16);
      u16* dst;
      if (MODE == 1) {
        dst = xb;
      } else {
        dst = (b * 8 + o < 64) ? xb : (u16*)outp;  // plane split, block-uniform
      }
      *(uint4*)(dst + idx) = u;
    }
  }
  // stats: wave butterfly -> LDS -> 16 global atomics
#pragma unroll
  for (int o = 0; o < 8; ++o) {
    float s = psum[o], q = psq[o];
#pragma unroll
    for (int mask = 32; mask >= 1; mask >>= 1) {
      s += __shfl_xor(s, mask, 64);
      q += __shfl_xor(q, mask, 64);
    }
    psum[o] = s; psq[o] = q;
  }
  const int lane = tid & 63;
  const int wid = tid >> 6;
  if (lane == 0) {
#pragma unroll
    for (int o = 0; o < 8; ++o) {
      sred[wid * 16 + o * 2] = psum[o];
      sred[wid * 16 + o * 2 + 1] = psq[o];
    }
  }
  __syncthreads();
  if (tid < 16) {
    float s = sred[tid] + sred[16 + tid] + sred[32 + tid] + sred[48 + tid];
    atomicAdd(&stats[tid], s);
  }
}

// ---------------- k3: BN normalize from fp16 staging -> f32 d_out ----------------
// src[e] is the fp16 of element e (absolute element indexing for both ws and
// d_out-resident staging). ebase selects the cascade slice.
__global__ void k3_fp16(const u16* __restrict__ src, float* __restrict__ outp,
                        const float* __restrict__ stats,
                        const float* __restrict__ gamma,
                        const float* __restrict__ beta,
                        const u32 ebase) {
  const size_t e0 = (size_t)ebase + ((size_t)blockIdx.x * 256 + threadIdx.x) * 8;
  const int o = (int)(e0 >> 16) & 7;
  const float inv_n = 1.0f / 4194304.0f;
  const float mean = stats[o * 2] * inv_n;
  float var = stats[o * 2 + 1] * inv_n - mean * mean;
  var = fmaxf(var, 0.0f);
  const float inv = rsqrtf(var + 1e-5f);
  const float g = gamma[o] * inv;
  const float sh = beta[o] - mean * g;
  const uint4 u = *(const uint4*)(src + e0);
  float f[8];
  f[0] = h2f((u16)(u.x & 0xffffu)); f[1] = h2f((u16)(u.x >> 16));
  f[2] = h2f((u16)(u.y & 0xffffu)); f[3] = h2f((u16)(u.y >> 16));
  f[4] = h2f((u16)(u.z & 0xffffu)); f[5] = h2f((u16)(u.z >> 16));
  f[6] = h2f((u16)(u.w & 0xffffu)); f[7] = h2f((u16)(u.w >> 16));
#pragma unroll
  for (int t = 0; t < 8; ++t) f[t] = fmaf(f[t], g, sh);
  st8f_nt(outp + e0, f);
}

// ---------------- k3: BN in place (f32 fallback) ----------------
__global__ void k3_norm_inplace(float* __restrict__ outp,
                                const float* __restrict__ stats,
                                const float* __restrict__ gamma,
                                const float* __restrict__ beta) {
  const int idx = blockIdx.x * 256 + threadIdx.x;
  const size_t e0 = (size_t)idx * 8;
  const int o = (int)(e0 >> 16) & 7;
  const float inv_n = 1.0f / 4194304.0f;
  const float mean = stats[o * 2] * inv_n;
  float var = stats[o * 2 + 1] * inv_n - mean * mean;
  var = fmaxf(var, 0.0f);
  const float inv = rsqrtf(var + 1e-5f);
  const float g = gamma[o] * inv;
  const float sh = beta[o] - mean * g;
  float f[8];
  ld8f(outp + e0, f);
#pragma unroll
  for (int t = 0; t < 8; ++t) f[t] = fmaf(f[t], g, sh);
  st8f_nt(outp + e0, f);
}

extern "C" void kernel_launch(void* const* d_in, const int* in_sizes, int n_in,
                              void* d_out, int out_size, void* d_ws, size_t ws_size,
                              hipStream_t stream) {
  const float* A  = (const float*)d_in[0];
  const float* P1 = (const float*)d_in[1];
  const float* P2 = (const float*)d_in[2];
  const float* P3 = (const float*)d_in[3];
  const float* P4 = (const float*)d_in[4];
  const float* P5 = (const float*)d_in[5];
  const float* Wq = (const float*)d_in[6];
  const float* Wk = (const float*)d_in[7];
  const float* gamma = (const float*)d_in[8];
  const float* beta  = (const float*)d_in[9];
  float* outp = (float*)d_out;

  float* stats = (float*)d_ws;
  float* mcab = (float*)((char*)d_ws + 256);                       // 4 MB
  u16* xb = (u16*)((char*)d_ws + 256 + (size_t)4 * 1024 * 1024);   // staging
  const size_t need_full = 256 + (size_t)4 * 1024 * 1024 + (size_t)2 * NTOT;
  const size_t need_casc = 256 + (size_t)4 * 1024 * 1024 + (size_t)2 * (NTOT / 8);

  hipLaunchKernelGGL(k1a_mmean, dim3(512), dim3(256), 0, stream, A, mcab, stats);
  hipLaunchKernelGGL(k1b_p2, dim3(512), dim3(256), 0, stream, mcab, P2);

  if (ws_size >= need_full) {
    hipLaunchKernelGGL((k2_main<1>), dim3(2048), dim3(256), 0, stream,
                       A, mcab, P1, P3, P4, P5, Wq, Wk, outp, xb, stats);
    hipLaunchKernelGGL(k3_fp16, dim3(16384), dim3(256), 0, stream,
                       xb, outp, stats, gamma, beta, 0u);
  } else if (ws_size >= need_casc) {
    hipLaunchKernelGGL((k2_main<2>), dim3(2048), dim3(256), 0, stream,
                       A, mcab, P1, P3, P4, P5, Wq, Wk, outp, xb, stats);
    // Cascade: high half first; each launch writes bytes [4e) disjoint from its
    // own reads [2e); subsequent launches may overwrite earlier launches' sources.
    hipLaunchKernelGGL(k3_fp16, dim3(8192), dim3(256), 0, stream,
                       (const u16*)outp, outp, stats, gamma, beta, (u32)(NTOT / 2));
    hipLaunchKernelGGL(k3_fp16, dim3(4096), dim3(256), 0, stream,
                       (const u16*)outp, outp, stats, gamma, beta, (u32)(NTOT / 4));
    hipLaunchKernelGGL(k3_fp16, dim3(2048), dim3(256), 0, stream,
                       (const u16*)outp, outp, stats, gamma, beta, (u32)(NTOT / 8));
    hipLaunchKernelGGL(k3_fp16, dim3(2048), dim3(256), 0, stream,
                       xb, outp, stats, gamma, beta, 0u);
  } else {
    hipLaunchKernelGGL((k2_main<0>), dim3(2048), dim3(256), 0, stream,
                       A, mcab, P1, P3, P4, P5, Wq, Wk, outp, xb, stats);
    hipLaunchKernelGGL(k3_norm_inplace, dim3(16384), dim3(256), 0, stream,
                       outp, stats, gamma, beta);
  }
}

// Round 3
// 387.316 us; speedup vs baseline: 1.0059x; 1.0059x over previous
//
#include <hip/hip_runtime.h>
#include <hip/hip_fp16.h>

// layer_3d_dep_53300544143949 — MI355X (gfx950)
// B=64, C=8, O=8, M=32, K=32, NR=8, NT=8. All inputs and output FLOAT32.
// R6 structure:
//   k1a: m-mean reduce, block=(b,c), 1024 thr (4-way m-split + LDS reduce) -> mc (ws, 4MB)
//        Full occupancy (32 waves/CU) vs R5's 8 waves/CU — latency-hiding fix.
//   k1b: in-place P2 transform mc -> a2pre (thread owns its 8 addresses; race-free)
//   k2:  main fold + attention (unchanged math, __launch_bounds__(256,2))
//        MODE 0: f32 pre-BN -> d_out (fallback)
//        MODE 1: fp16 pre-BN -> ws staging (ws >= 68.2MB)
//        MODE 2: fp16 split by rsplit R: e >= R -> d_out at byte 2e; e < R -> ws (2R bytes)
//   k3:  BN normalize. MODE 2 cascade, top-down slices [S,2S): reads fp16 bytes [2S,4S),
//        writes f32 bytes [4S,8S) — disjoint per launch; stream order retires each
//        region before overwrite. Bottom [0,R) from ws. R adapts to ws_size (min 128KB).
// ws: [0,256) stats | [256, 256+4MB) mc/a2pre f32 | [+4MB, ...) fp16 staging (2R bytes)

using u16 = unsigned short;
using u32 = unsigned int;
typedef float f32x4 __attribute__((ext_vector_type(4)));

#define NTOT 33554432u  // total output elements = 64*8*32*32*8*8
#define PLANE 65536u    // elements per (b,o) plane

__device__ __forceinline__ void ld8f(const float* p, float* f) {
  float4 a = *(const float4*)p;
  float4 b = *(const float4*)(p + 4);
  f[0] = a.x; f[1] = a.y; f[2] = a.z; f[3] = a.w;
  f[4] = b.x; f[5] = b.y; f[6] = b.z; f[7] = b.w;
}
__device__ __forceinline__ void st8f(float* p, const float* f) {
  *(float4*)p = make_float4(f[0], f[1], f[2], f[3]);
  *(float4*)(p + 4) = make_float4(f[4], f[5], f[6], f[7]);
}
__device__ __forceinline__ void st8f_nt(float* p, const float* f) {
  f32x4 a = {f[0], f[1], f[2], f[3]};
  f32x4 b = {f[4], f[5], f[6], f[7]};
  __builtin_nontemporal_store(a, (f32x4*)p);
  __builtin_nontemporal_store(b, (f32x4*)(p + 4));
}
__device__ __forceinline__ u16 f2h(float f) {
  __half h = __float2half_rn(f);
  return *(u16*)&h;
}
__device__ __forceinline__ float h2f(u16 x) {
  __half h = *(__half*)&x;
  return __half2float(h);
}
__device__ __forceinline__ float fast_tanh(float x) {
  float e = __expf(2.0f * x);
  return 1.0f - 2.0f / (e + 1.0f);
}

// ---------------- k1a: m-mean reduce (1024 thr, LDS reduce) ----------------
// grid 512 = b*8+c; 1024 thr = (mh:4) x (jt:256). Thread sums 8 m-slices of
// j = jt*8..jt*8+7 (32B coalesced loads); LDS reduce across mh; mh==0 writes mc.
__global__ __launch_bounds__(1024) void k1a_mmean(
    const float* __restrict__ A, float* __restrict__ mcab,
    float* __restrict__ stats) {
  __shared__ float red[4][256][9];  // stride 9 floats: conflict-free reduce reads
  const int b = blockIdx.x >> 3;
  const int c = blockIdx.x & 7;
  const int tid = threadIdx.x;
  if (blockIdx.x == 0 && tid < 16) stats[tid] = 0.0f;
  const int mh = tid >> 8;   // 0..3
  const int jt = tid & 255;  // j-octet
  const float* base = A + (size_t)(b * 8 + c) * 65536 + (size_t)mh * 8 * 2048 + jt * 8;
  float acc[8];
#pragma unroll
  for (int t = 0; t < 8; ++t) acc[t] = 0.0f;
#pragma unroll
  for (int m = 0; m < 8; ++m) {
    float ar[8];
    ld8f(base + m * 2048, ar);
#pragma unroll
    for (int t = 0; t < 8; ++t) acc[t] += ar[t];
  }
#pragma unroll
  for (int t = 0; t < 8; ++t) red[mh][jt][t] = acc[t];
  __syncthreads();
  if (mh == 0) {
    float s[8];
#pragma unroll
    for (int t = 0; t < 8; ++t)
      s[t] = (red[0][jt][t] + red[1][jt][t] + red[2][jt][t] + red[3][jt][t]) *
             (1.0f / 32.0f);
    st8f(mcab + (size_t)(b * 8 + c) * 2048 + jt * 8, s);
  }
}

// ---------------- k1b: in-place P2 transform mc -> a2pre ----------------
// Thread owns (b, j): reads mc[b,0..8,j], writes a2pre[b,0..8,j] over the same
// 8 addresses. Address set is thread-private -> no cross-thread hazard.
__global__ void k1b_p2(float* __restrict__ mcab, const float* __restrict__ P2) {
  const int b = blockIdx.x >> 3;
  const int j = (blockIdx.x & 7) * 256 + threadIdx.x;
  float mc[8];
#pragma unroll
  for (int c = 0; c < 8; ++c) mc[c] = mcab[(size_t)(b * 8 + c) * 2048 + j];
  float a2[8];
#pragma unroll
  for (int o = 0; o < 8; ++o) {
    float s = 0.0f;
#pragma unroll
    for (int c = 0; c < 8; ++c) s = fmaf(P2[o * 8 + c], mc[c], s);
    a2[o] = 0.1f * s;
  }
#pragma unroll
  for (int o = 0; o < 8; ++o) mcab[(size_t)(b * 8 + o) * 2048 + j] = a2[o];
}

// ---------------- k2: main ----------------
// grid 2048 = (b<<5)|m; 256 thr. (k,r): k=tid>>3, r=tid&7.
template <int MODE>
__global__ __launch_bounds__(256, 2) void k2_main(
    const float* __restrict__ A,
    const float* __restrict__ a2pre,
    const float* __restrict__ P1,
    const float* __restrict__ P3,
    const float* __restrict__ P4,
    const float* __restrict__ P5,
    const float* __restrict__ Wq,
    const float* __restrict__ Wk,
    float* __restrict__ outp,      // MODE 0: f32 out; MODE 2: also fp16 target
    u16* __restrict__ xb,          // MODE 1: full staging; MODE 2: e < rsplit
    float* __restrict__ stats,
    const u32 rsplit) {
  __shared__ float qb[8 * 260];
  __shared__ float kb[8 * 260];
  __shared__ float vb[8 * 260];
  __shared__ float a5b[8 * 260];
  __shared__ float sred[64];

  const int tid = threadIdx.x;
  const int b = blockIdx.x >> 5;
  const int m = blockIdx.x & 31;
  const int k = tid >> 3;
  const int r = tid & 7;

  float acc[8][8];
  float acc3[8];
  float qv[8], kv[8], vv[8];
#pragma unroll
  for (int o = 0; o < 8; ++o) {
    acc3[o] = 0.0f;
#pragma unroll
    for (int t = 0; t < 8; ++t) acc[o][t] = 0.0f;
  }
#pragma unroll
  for (int t = 0; t < 8; ++t) { qv[t] = 0.0f; kv[t] = 0.0f; vv[t] = 0.0f; }

  // Single c-loop: load A row; trc via lane-xor means; fold A1/A4 per-t,
  // A3 hoisted to scalar acc3[o]; accumulate qkv (o = r lane mapping).
#pragma unroll
  for (int c = 0; c < 8; ++c) {
    float ar[8];
    ld8f(A + ((size_t)((b * 8 + c) * 32 + m) * 2048 + tid * 8), ar);
    float trc[8];
#pragma unroll
    for (int t = 0; t < 8; ++t) {
      float x = ar[t];
      x += __shfl_xor(x, 1, 64);
      x += __shfl_xor(x, 2, 64);
      x += __shfl_xor(x, 4, 64);
      trc[t] = x * 0.125f;
    }
    const float mtc = (ar[0] + ar[1] + ar[2] + ar[3] +
                       ar[4] + ar[5] + ar[6] + ar[7]) * 0.125f;
#pragma unroll
    for (int o = 0; o < 8; ++o) {
      const float w1 = P1[o * 8 + c];
      const float w4 = 0.5f * P4[o * 8 + c];
      acc3[o] = fmaf(0.1f * P3[o * 8 + c], mtc, acc3[o]);
#pragma unroll
      for (int t = 0; t < 8; ++t)
        acc[o][t] = fmaf(w1, ar[t], fmaf(w4, trc[t], acc[o][t]));
    }
    const float wq = Wq[r * 8 + c];
    const float wk = Wk[r * 8 + c];
    const float wv = P5[r * 8 + c];
#pragma unroll
    for (int t = 0; t < 8; ++t) {
      qv[t] = fmaf(wq, trc[t], qv[t]);
      kv[t] = fmaf(wk, trc[t], kv[t]);
      vv[t] = fmaf(wv, trc[t], vv[t]);
    }
  }

  // A2 (precomputed, m-independent) + A3 broadcast
#pragma unroll
  for (int o = 0; o < 8; ++o) {
    float a2v[8];
    ld8f(a2pre + ((size_t)(b * 8 + o) * 2048 + tid * 8), a2v);
#pragma unroll
    for (int t = 0; t < 8; ++t) acc[o][t] += a2v[t] + acc3[o];
  }

  st8f(&qb[r * 260 + k * 8], qv);
  st8f(&kb[r * 260 + k * 8], kv);
  st8f(&vb[r * 260 + k * 8], vv);
  __syncthreads();

  // Attention: thread = (o, kq, lo): 4 k-rows x 8 l-rows register tile
  {
    const int o = tid >> 5;
    const int kq = (tid >> 2) & 7;
    const int lo = tid & 3;
    float qf[4][8];
#pragma unroll
    for (int kl = 0; kl < 4; ++kl)
      ld8f(&qb[o * 260 + (kq * 4 + kl) * 8], qf[kl]);
    float a5p[4][8];
#pragma unroll
    for (int kl = 0; kl < 4; ++kl)
#pragma unroll
      for (int t = 0; t < 8; ++t) a5p[kl][t] = 0.0f;

#pragma unroll
    for (int ll = 0; ll < 8; ++ll) {
      const int l = lo * 8 + ll;
      float krw[8];
      ld8f(&kb[o * 260 + l * 8], krw);
      float al[4];
#pragma unroll
      for (int kl = 0; kl < 4; ++kl) {
        float s = 0.0f;
#pragma unroll
        for (int t = 0; t < 8; ++t) s = fmaf(qf[kl][t], krw[t], s);
        al[kl] = fast_tanh(s * 0.125f);  // /NT
      }
      float vrw[8];
      ld8f(&vb[o * 260 + l * 8], vrw);
#pragma unroll
      for (int kl = 0; kl < 4; ++kl)
#pragma unroll
        for (int t = 0; t < 8; ++t)
          a5p[kl][t] = fmaf(al[kl], vrw[t], a5p[kl][t]);
    }
#pragma unroll
    for (int kl = 0; kl < 4; ++kl)
#pragma unroll
      for (int t = 0; t < 8; ++t) {
        float x = a5p[kl][t];
        x += __shfl_xor(x, 1, 64);
        x += __shfl_xor(x, 2, 64);
        a5p[kl][t] = x * 0.0625f;  // 2/Kd
      }
#pragma unroll
    for (int kl = 0; kl < 4; ++kl) {
      const float w0 = lo == 0 ? a5p[kl][0] : lo == 1 ? a5p[kl][2]
                      : lo == 2 ? a5p[kl][4] : a5p[kl][6];
      const float w1 = lo == 0 ? a5p[kl][1] : lo == 1 ? a5p[kl][3]
                      : lo == 2 ? a5p[kl][5] : a5p[kl][7];
      *(float2*)&a5b[o * 260 + (kq * 4 + kl) * 8 + lo * 2] = make_float2(w0, w1);
    }
  }
  __syncthreads();

  // Epilogue: +A5, ReLU, stats, store pre-BN
  float psum[8], psq[8];
#pragma unroll
  for (int o = 0; o < 8; ++o) { psum[o] = 0.0f; psq[o] = 0.0f; }
  const size_t outbase = (size_t)(b * 256 + m) * 2048 + tid * 8;
#pragma unroll
  for (int o = 0; o < 8; ++o) {
    float a5f[8];
    ld8f(&a5b[o * 260 + k * 8], a5f);
    float x8[8];
#pragma unroll
    for (int t = 0; t < 8; ++t) {
      float x = acc[o][t] + a5f[t];
      x = fmaxf(x, 0.0f);
      psum[o] += x;
      psq[o] = fmaf(x, x, psq[o]);
      x8[t] = x;
    }
    const size_t idx = outbase + (size_t)o * 65536;
    if (MODE == 0) {
      st8f(outp + idx, x8);
    } else {
      uint4 u;
      u.x = (u32)f2h(x8[0]) | ((u32)f2h(x8[1]) << 16);
      u.y = (u32)f2h(x8[2]) | ((u32)f2h(x8[3]) << 16);
      u.z = (u32)f2h(x8[4]) | ((u32)f2h(x8[5]) << 16);
      u.w = (u32)f2h(x8[6]) | ((u32)f2h(x8[7]) << 16);
      u16* dst;
      if (MODE == 1) {
        dst = xb;
      } else {
        dst = (idx >= (size_t)rsplit) ? (u16*)outp : xb;  // plane-aligned split
      }
      *(uint4*)(dst + idx) = u;
    }
  }
  // stats: wave butterfly -> LDS -> 16 global atomics
#pragma unroll
  for (int o = 0; o < 8; ++o) {
    float s = psum[o], q = psq[o];
#pragma unroll
    for (int mask = 32; mask >= 1; mask >>= 1) {
      s += __shfl_xor(s, mask, 64);
      q += __shfl_xor(q, mask, 64);
    }
    psum[o] = s; psq[o] = q;
  }
  const int lane = tid & 63;
  const int wid = tid >> 6;
  if (lane == 0) {
#pragma unroll
    for (int o = 0; o < 8; ++o) {
      sred[wid * 16 + o * 2] = psum[o];
      sred[wid * 16 + o * 2 + 1] = psq[o];
    }
  }
  __syncthreads();
  if (tid < 16) {
    float s = sred[tid] + sred[16 + tid] + sred[32 + tid] + sred[48 + tid];
    atomicAdd(&stats[tid], s);
  }
}

// ---------------- k3: BN normalize from fp16 staging -> f32 d_out ----------------
// src[e] is the fp16 of element e (absolute element indexing for both ws and
// d_out-resident staging). ebase selects the cascade slice.
__global__ void k3_fp16(const u16* __restrict__ src, float* __restrict__ outp,
                        const float* __restrict__ stats,
                        const float* __restrict__ gamma,
                        const float* __restrict__ beta,
                        const u32 ebase) {
  const size_t e0 = (size_t)ebase + ((size_t)blockIdx.x * 256 + threadIdx.x) * 8;
  const int o = (int)(e0 >> 16) & 7;
  const float inv_n = 1.0f / 4194304.0f;
  const float mean = stats[o * 2] * inv_n;
  float var = stats[o * 2 + 1] * inv_n - mean * mean;
  var = fmaxf(var, 0.0f);
  const float inv = rsqrtf(var + 1e-5f);
  const float g = gamma[o] * inv;
  const float sh = beta[o] - mean * g;
  const uint4 u = *(const uint4*)(src + e0);
  float f[8];
  f[0] = h2f((u16)(u.x & 0xffffu)); f[1] = h2f((u16)(u.x >> 16));
  f[2] = h2f((u16)(u.y & 0xffffu)); f[3] = h2f((u16)(u.y >> 16));
  f[4] = h2f((u16)(u.z & 0xffffu)); f[5] = h2f((u16)(u.z >> 16));
  f[6] = h2f((u16)(u.w & 0xffffu)); f[7] = h2f((u16)(u.w >> 16));
#pragma unroll
  for (int t = 0; t < 8; ++t) f[t] = fmaf(f[t], g, sh);
  st8f_nt(outp + e0, f);
}

// ---------------- k3: BN in place (f32 fallback) ----------------
__global__ void k3_norm_inplace(float* __restrict__ outp,
                                const float* __restrict__ stats,
                                const float* __restrict__ gamma,
                                const float* __restrict__ beta) {
  const int idx = blockIdx.x * 256 + threadIdx.x;
  const size_t e0 = (size_t)idx * 8;
  const int o = (int)(e0 >> 16) & 7;
  const float inv_n = 1.0f / 4194304.0f;
  const float mean = stats[o * 2] * inv_n;
  float var = stats[o * 2 + 1] * inv_n - mean * mean;
  var = fmaxf(var, 0.0f);
  const float inv = rsqrtf(var + 1e-5f);
  const float g = gamma[o] * inv;
  const float sh = beta[o] - mean * g;
  float f[8];
  ld8f(outp + e0, f);
#pragma unroll
  for (int t = 0; t < 8; ++t) f[t] = fmaf(f[t], g, sh);
  st8f_nt(outp + e0, f);
}

extern "C" void kernel_launch(void* const* d_in, const int* in_sizes, int n_in,
                              void* d_out, int out_size, void* d_ws, size_t ws_size,
                              hipStream_t stream) {
  const float* A  = (const float*)d_in[0];
  const float* P1 = (const float*)d_in[1];
  const float* P2 = (const float*)d_in[2];
  const float* P3 = (const float*)d_in[3];
  const float* P4 = (const float*)d_in[4];
  const float* P5 = (const float*)d_in[5];
  const float* Wq = (const float*)d_in[6];
  const float* Wk = (const float*)d_in[7];
  const float* gamma = (const float*)d_in[8];
  const float* beta  = (const float*)d_in[9];
  float* outp = (float*)d_out;

  float* stats = (float*)d_ws;
  float* mcab = (float*)((char*)d_ws + 256);                       // 4 MB
  u16* xb = (u16*)((char*)d_ws + 256 + (size_t)4 * 1024 * 1024);   // staging
  const size_t UWB = 256 + (size_t)4 * 1024 * 1024;
  const size_t need_full = UWB + (size_t)2 * NTOT;

  hipLaunchKernelGGL(k1a_mmean, dim3(512), dim3(1024), 0, stream, A, mcab, stats);
  hipLaunchKernelGGL(k1b_p2, dim3(512), dim3(256), 0, stream, mcab, P2);

  if (ws_size >= need_full) {
    // Full fp16 staging in ws, single k3.
    hipLaunchKernelGGL((k2_main<1>), dim3(2048), dim3(256), 0, stream,
                       A, mcab, P1, P3, P4, P5, Wq, Wk, outp, xb, stats, 0u);
    hipLaunchKernelGGL(k3_fp16, dim3(16384), dim3(256), 0, stream,
                       xb, outp, stats, gamma, beta, 0u);
  } else {
    const size_t avail = (ws_size > UWB) ? (ws_size - UWB) : 0;
    u32 R = NTOT / 2;
    while (R > PLANE && (size_t)2 * R > avail) R >>= 1;
    if ((size_t)2 * R <= avail) {
      // fp16 split: e >= R staged in d_out at byte 2e; e < R staged in ws.
      hipLaunchKernelGGL((k2_main<2>), dim3(2048), dim3(256), 0, stream,
                         A, mcab, P1, P3, P4, P5, Wq, Wk, outp, xb, stats, R);
      // Cascade top-down: slice [S,2S) reads fp16 bytes [2S,4S), writes f32
      // bytes [4S,8S) — disjoint; stream order retires regions before overwrite.
      for (u32 S = NTOT / 2; S >= R; S >>= 1) {
        hipLaunchKernelGGL(k3_fp16, dim3(S / 2048), dim3(256), 0, stream,
                           (const u16*)outp, outp, stats, gamma, beta, S);
      }
      hipLaunchKernelGGL(k3_fp16, dim3(R / 2048), dim3(256), 0, stream,
                         xb, outp, stats, gamma, beta, 0u);
    } else {
      hipLaunchKernelGGL((k2_main<0>), dim3(2048), dim3(256), 0, stream,
                         A, mcab, P1, P3, P4, P5, Wq, Wk, outp, xb, stats, 0u);
      hipLaunchKernelGGL(k3_norm_inplace, dim3(16384), dim3(256), 0, stream,
                         outp, stats, gamma, beta);
    }
  }
}